// Round 6
// baseline (27.509 us; speedup 1.0000x reference)
//
#include <hip/hip_runtime.h>

// SeparableWeightedConv R5: R4 with compile fix (native clang vector for the
// nontemporal store). CH=8/1024 blocks, __launch_bounds__(256,4) occupancy
// pin, register diet, SGPR-hoisted weights, fully-unrolled channel loop with
// 1-deep prefetch, nontemporal out stores.

#define BB 8
#define CC 128
#define NN 8192
#define KK 9

constexpr int CH      = 8;            // channels per block
constexpr int CGROUPS = CC / CH;      // 16
constexpr int LTILE   = 1024;         // 256 thr x 4 l
constexpr int LTILES  = NN / LTILE;   // 8
constexpr int THREADS = 256;

typedef float vfloat4 __attribute__((ext_vector_type(4)));   // native clang vector

__device__ __forceinline__ void load12(const float* __restrict__ p, int l0, bool interior,
                                       float4& A, float4& B, float4& C) {
    if (interior) {
        A = *(const float4*)(p + l0 - 4);
        B = *(const float4*)(p + l0);
        C = *(const float4*)(p + l0 + 4);
    } else {
        float t[12];
        #pragma unroll
        for (int j = 0; j < 12; ++j) {
            int q = l0 - 4 + j;
            t[j] = (q >= 0 && q < NN) ? p[q] : 0.0f;    // zero-pad (x path)
        }
        A = make_float4(t[0], t[1], t[2], t[3]);
        B = make_float4(t[4], t[5], t[6], t[7]);
        C = make_float4(t[8], t[9], t[10], t[11]);
    }
}

__global__ __launch_bounds__(THREADS, 4)
void sepwconv_kernel(const float* __restrict__ x,
                     const float* __restrict__ coords,
                     const float* __restrict__ sigma,
                     const float* __restrict__ weight,
                     float* __restrict__ out)
{
    const int bid = blockIdx.x;
    const int cg  = bid % CGROUPS;
    const int lt  = (bid / CGROUPS) % LTILES;
    const int b   = bid / (CGROUPS * LTILES);
    const int t   = threadIdx.x;
    const int l0  = lt * LTILE + t * 4;
    const bool interior = (l0 >= 4) && (l0 + 8 <= NN);
    const float inv_sigma = 1.0f / sigma[0];

    // ---- issue all coord window loads (9 independent float4s) ----
    const float* cbase = coords + (size_t)b * 3 * NN;
    float cw[3][12];
    if (interior) {
        #pragma unroll
        for (int dim = 0; dim < 3; ++dim) {
            const float* src = cbase + (size_t)dim * NN;
            float4 A  = *(const float4*)(src + l0 - 4);
            float4 Bq = *(const float4*)(src + l0);
            float4 Cq = *(const float4*)(src + l0 + 4);
            cw[dim][0]=A.x; cw[dim][1]=A.y; cw[dim][2]=A.z; cw[dim][3]=A.w;
            cw[dim][4]=Bq.x;cw[dim][5]=Bq.y;cw[dim][6]=Bq.z;cw[dim][7]=Bq.w;
            cw[dim][8]=Cq.x;cw[dim][9]=Cq.y;cw[dim][10]=Cq.z;cw[dim][11]=Cq.w;
        }
    } else {
        #pragma unroll
        for (int dim = 0; dim < 3; ++dim) {
            const float* src = cbase + (size_t)dim * NN;
            #pragma unroll
            for (int j = 0; j < 12; ++j) {
                int p = l0 - 4 + j;
                p = p < 0 ? 0 : (p >= NN ? NN - 1 : p);  // clamp: OOB taps hit x==0
                cw[dim][j] = src[p];
            }
        }
    }

    // ---- issue channel-0 x loads early (overlap with sqrt chain) ----
    const float* xbase = x + ((size_t)b * CC + cg * CH) * NN;
    float4 XA, XB, XC;
    load12(xbase, l0, interior, XA, XB, XC);

    // ---- hoist ALL channel weights into SGPRs (uniform addresses) ----
    float wsg[CH][KK];
    {
        const float* wr = weight + (size_t)cg * CH * KK;
        #pragma unroll
        for (int i = 0; i < CH; ++i)
            #pragma unroll
            for (int k = 0; k < KK; ++k)
                wsg[i][k] = wr[i * KK + k];
    }

    // ---- dw[4][K]: accumulate sq distance dim-by-dim (retires cw regs) ----
    float dw[4][KK];
    #pragma unroll
    for (int jl = 0; jl < 4; ++jl)
        #pragma unroll
        for (int k = 0; k < KK; ++k) {
            const float d0 = cw[0][jl + k] - cw[0][jl + 4];
            dw[jl][k] = d0 * d0;
        }
    #pragma unroll
    for (int dim = 1; dim < 3; ++dim)
        #pragma unroll
        for (int jl = 0; jl < 4; ++jl)
            #pragma unroll
            for (int k = 0; k < KK; ++k) {
                const float d = cw[dim][jl + k] - cw[dim][jl + 4];
                dw[jl][k] = fmaf(d, d, dw[jl][k]);
            }
    #pragma unroll
    for (int jl = 0; jl < 4; ++jl)
        #pragma unroll
        for (int k = 0; k < KK; ++k) {
            const float dist = sqrtf(dw[jl][k]);        // sqrt(0)==0 matches ref
            dw[jl][k] = fmaxf(fmaf(-inv_sigma, dist, 1.0f), 0.0f);
        }

    // ---- fully-unrolled channel loop with 1-deep prefetch ----
    #pragma unroll
    for (int i = 0; i < CH; ++i) {
        float4 NA, NB, NC;
        if (i + 1 < CH) load12(xbase + (size_t)(i + 1) * NN, l0, interior, NA, NB, NC);

        const float xv[12] = {XA.x,XA.y,XA.z,XA.w, XB.x,XB.y,XB.z,XB.w, XC.x,XC.y,XC.z,XC.w};

        float acc[4] = {0.f, 0.f, 0.f, 0.f};
        #pragma unroll
        for (int jl = 0; jl < 4; ++jl)
            #pragma unroll
            for (int k = 0; k < KK; ++k)
                acc[jl] = fmaf(xv[jl + k] * dw[jl][k], wsg[i][k], acc[jl]);

        vfloat4 o = {acc[0], acc[1], acc[2], acc[3]};
        __builtin_nontemporal_store(o, (vfloat4*)(out + ((size_t)b * CC + cg * CH + i) * NN + l0));

        if (i + 1 < CH) { XA = NA; XB = NB; XC = NC; }
    }
}

extern "C" void kernel_launch(void* const* d_in, const int* in_sizes, int n_in,
                              void* d_out, int out_size, void* d_ws, size_t ws_size,
                              hipStream_t stream) {
    const float* x      = (const float*)d_in[0];
    const float* coords = (const float*)d_in[1];
    const float* sigma  = (const float*)d_in[2];
    const float* weight = (const float*)d_in[3];
    float* out = (float*)d_out;

    dim3 grid(BB * LTILES * CGROUPS);   // 1024 blocks
    sepwconv_kernel<<<grid, THREADS, 0, stream>>>(x, coords, sigma, weight, out);
}

// Round 8
// 23.071 us; speedup vs baseline: 1.1924x; 1.1924x over previous
//
#include <hip/hip_runtime.h>

// SeparableWeightedConv R7: R6 with compile fix (__builtin_amdgcn_sqrtf ->
// single v_sqrt_f32). Two deltas vs the R1 champion:
//  (1) raw-HW sqrt in the dw prologue (threshold has 15x headroom)
//  (2) channel loop hand-unrolled, 3 named rotating buffers, 2-deep prefetch

#define BB 8
#define CC 128
#define NN 8192
#define KK 9

constexpr int CH      = 8;            // channels per block
constexpr int CGROUPS = CC / CH;      // 16
constexpr int LTILE   = 1024;         // 256 thr x 4 l
constexpr int LTILES  = NN / LTILE;   // 8
constexpr int THREADS = 256;

__device__ __forceinline__ void load12(const float* __restrict__ p, int l0, bool interior,
                                       float4& A, float4& B, float4& C) {
    if (interior) {
        A = *(const float4*)(p + l0 - 4);
        B = *(const float4*)(p + l0);
        C = *(const float4*)(p + l0 + 4);
    } else {
        float t[12];
        #pragma unroll
        for (int j = 0; j < 12; ++j) {
            int q = l0 - 4 + j;
            t[j] = (q >= 0 && q < NN) ? p[q] : 0.0f;   // zero-pad (x path)
        }
        A = make_float4(t[0], t[1], t[2], t[3]);
        B = make_float4(t[4], t[5], t[6], t[7]);
        C = make_float4(t[8], t[9], t[10], t[11]);
    }
}

__global__ __launch_bounds__(THREADS)
void sepwconv_kernel(const float* __restrict__ x,
                     const float* __restrict__ coords,
                     const float* __restrict__ sigma,
                     const float* __restrict__ weight,
                     float* __restrict__ out)
{
    const int bid = blockIdx.x;
    const int cg  = bid % CGROUPS;
    const int lt  = (bid / CGROUPS) % LTILES;
    const int b   = bid / (CGROUPS * LTILES);
    const int t   = threadIdx.x;
    const int l0  = lt * LTILE + t * 4;

    const bool interior = (l0 >= 4) && (l0 + 8 <= NN);
    const float inv_sigma = 1.0f / sigma[0];

    const float* cx = coords + (size_t)(b * 3 + 0) * NN;
    const float* cy = coords + (size_t)(b * 3 + 1) * NN;
    const float* cz = coords + (size_t)(b * 3 + 2) * NN;

    // --- coord window loads ---
    float cxv[12], cyv[12], czv[12];
    if (interior) {
        float4 a, bq, cq;
        a = *(const float4*)(cx + l0 - 4); bq = *(const float4*)(cx + l0); cq = *(const float4*)(cx + l0 + 4);
        cxv[0]=a.x;cxv[1]=a.y;cxv[2]=a.z;cxv[3]=a.w; cxv[4]=bq.x;cxv[5]=bq.y;cxv[6]=bq.z;cxv[7]=bq.w; cxv[8]=cq.x;cxv[9]=cq.y;cxv[10]=cq.z;cxv[11]=cq.w;
        a = *(const float4*)(cy + l0 - 4); bq = *(const float4*)(cy + l0); cq = *(const float4*)(cy + l0 + 4);
        cyv[0]=a.x;cyv[1]=a.y;cyv[2]=a.z;cyv[3]=a.w; cyv[4]=bq.x;cyv[5]=bq.y;cyv[6]=bq.z;cyv[7]=bq.w; cyv[8]=cq.x;cyv[9]=cq.y;cyv[10]=cq.z;cyv[11]=cq.w;
        a = *(const float4*)(cz + l0 - 4); bq = *(const float4*)(cz + l0); cq = *(const float4*)(cz + l0 + 4);
        czv[0]=a.x;czv[1]=a.y;czv[2]=a.z;czv[3]=a.w; czv[4]=bq.x;czv[5]=bq.y;czv[6]=bq.z;czv[7]=bq.w; czv[8]=cq.x;czv[9]=cq.y;czv[10]=cq.z;czv[11]=cq.w;
    } else {
        #pragma unroll
        for (int j = 0; j < 12; ++j) {
            int p = l0 - 4 + j;
            p = p < 0 ? 0 : (p >= NN ? NN - 1 : p);  // clamp: OOB taps hit x==0 anyway
            cxv[j] = cx[p]; cyv[j] = cy[p]; czv[j] = cz[p];
        }
    }

    // --- 2-deep prefetch: issue ch0 + ch1 x loads before the sqrt chain ---
    const float* xbase = x + ((size_t)b * CC + cg * CH) * NN;
    float4 A0,B0,C0, A1,B1,C1, A2,B2,C2;
    load12(xbase,                  l0, interior, A0, B0, C0);   // ch 0
    load12(xbase + (size_t)1 * NN, l0, interior, A1, B1, C1);   // ch 1

    // --- dw[jl][k]: distance weights, shared across channels ---
    float dw[4][KK];
    #pragma unroll
    for (int jl = 0; jl < 4; ++jl) {
        const float ccx = cxv[jl + 4], ccy = cyv[jl + 4], ccz = czv[jl + 4];
        #pragma unroll
        for (int k = 0; k < KK; ++k) {
            const float dx = cxv[jl + k] - ccx;
            const float dy = cyv[jl + k] - ccy;
            const float dz = czv[jl + k] - ccz;
            const float sq = fmaf(dx, dx, fmaf(dy, dy, dz * dz));
            const float dist = __builtin_amdgcn_sqrtf(sq);   // v_sqrt_f32; sqrt(0)==0
            dw[jl][k] = fmaxf(fmaf(-inv_sigma, dist, 1.0f), 0.0f);
        }
    }

    // --- compute helper (static channel index) ---
    auto compute = [&](int i, const float4& XA, const float4& XB, const float4& XC) {
        const float* wr = weight + (size_t)(cg * CH + i) * KK;  // wave-uniform
        float w[KK];
        #pragma unroll
        for (int k = 0; k < KK; ++k) w[k] = wr[k];

        const float xv[12] = {XA.x,XA.y,XA.z,XA.w, XB.x,XB.y,XB.z,XB.w, XC.x,XC.y,XC.z,XC.w};
        float acc[4] = {0.f, 0.f, 0.f, 0.f};
        #pragma unroll
        for (int jl = 0; jl < 4; ++jl)
            #pragma unroll
            for (int k = 0; k < KK; ++k)
                acc[jl] = fmaf(xv[jl + k] * dw[jl][k], w[k], acc[jl]);

        float4 o; o.x = acc[0]; o.y = acc[1]; o.z = acc[2]; o.w = acc[3];
        *(float4*)(out + ((size_t)b * CC + cg * CH + i) * NN + l0) = o;
    };

    // --- hand-pipelined channel sequence: load ch i+2 while computing ch i ---
    load12(xbase + (size_t)2 * NN, l0, interior, A2, B2, C2);
    compute(0, A0, B0, C0);
    load12(xbase + (size_t)3 * NN, l0, interior, A0, B0, C0);
    compute(1, A1, B1, C1);
    load12(xbase + (size_t)4 * NN, l0, interior, A1, B1, C1);
    compute(2, A2, B2, C2);
    load12(xbase + (size_t)5 * NN, l0, interior, A2, B2, C2);
    compute(3, A0, B0, C0);
    load12(xbase + (size_t)6 * NN, l0, interior, A0, B0, C0);
    compute(4, A1, B1, C1);
    load12(xbase + (size_t)7 * NN, l0, interior, A1, B1, C1);
    compute(5, A2, B2, C2);
    compute(6, A0, B0, C0);
    compute(7, A1, B1, C1);
}

extern "C" void kernel_launch(void* const* d_in, const int* in_sizes, int n_in,
                              void* d_out, int out_size, void* d_ws, size_t ws_size,
                              hipStream_t stream) {
    const float* x      = (const float*)d_in[0];
    const float* coords = (const float*)d_in[1];
    const float* sigma  = (const float*)d_in[2];
    const float* weight = (const float*)d_in[3];
    float* out = (float*)d_out;

    dim3 grid(BB * LTILES * CGROUPS);   // 1024 blocks
    sepwconv_kernel<<<grid, THREADS, 0, stream>>>(x, coords, sigma, weight, out);
}

// Round 9
// 18.883 us; speedup vs baseline: 1.4568x; 1.2218x over previous
//
#include <hip/hip_runtime.h>

// SeparableWeightedConv R8: shuffle-halo x loads.
// Each thread loads ONLY its center quad M = x[l0..l0+3] (16B = its output
// bytes); left/right halo quads come from lane+-1 via __shfl (they're those
// lanes' M). Only lane 0/63 per wave do a real (predicated, prefetched) halo
// load. Cuts x load-path traffic 3x (96MB -> 33MB). Keeps R7's fast sqrt and
// 1-deep pipeline (2-deep was neutral).

#define BB 8
#define CC 128
#define NN 8192
#define KK 9

constexpr int CH      = 8;            // channels per block
constexpr int CGROUPS = CC / CH;      // 16
constexpr int LTILE   = 1024;         // 256 thr x 4 l
constexpr int LTILES  = NN / LTILE;   // 8
constexpr int THREADS = 256;

struct Stage { float4 M, L, R; };     // L/R only meaningful on lanes 0/63

__global__ __launch_bounds__(THREADS)
void sepwconv_kernel(const float* __restrict__ x,
                     const float* __restrict__ coords,
                     const float* __restrict__ sigma,
                     const float* __restrict__ weight,
                     float* __restrict__ out)
{
    const int bid = blockIdx.x;
    const int cg  = bid % CGROUPS;
    const int lt  = (bid / CGROUPS) % LTILES;
    const int b   = bid / (CGROUPS * LTILES);
    const int t   = threadIdx.x;
    const int lane = t & 63;
    const int l0  = lt * LTILE + t * 4;

    const bool interior = (l0 >= 4) && (l0 + 8 <= NN);
    const float inv_sigma = 1.0f / sigma[0];

    const float* cx = coords + (size_t)(b * 3 + 0) * NN;
    const float* cy = coords + (size_t)(b * 3 + 1) * NN;
    const float* cz = coords + (size_t)(b * 3 + 2) * NN;

    // --- coord window loads (unchanged from R1/R7) ---
    float cxv[12], cyv[12], czv[12];
    if (interior) {
        float4 a, bq, cq;
        a = *(const float4*)(cx + l0 - 4); bq = *(const float4*)(cx + l0); cq = *(const float4*)(cx + l0 + 4);
        cxv[0]=a.x;cxv[1]=a.y;cxv[2]=a.z;cxv[3]=a.w; cxv[4]=bq.x;cxv[5]=bq.y;cxv[6]=bq.z;cxv[7]=bq.w; cxv[8]=cq.x;cxv[9]=cq.y;cxv[10]=cq.z;cxv[11]=cq.w;
        a = *(const float4*)(cy + l0 - 4); bq = *(const float4*)(cy + l0); cq = *(const float4*)(cy + l0 + 4);
        cyv[0]=a.x;cyv[1]=a.y;cyv[2]=a.z;cyv[3]=a.w; cyv[4]=bq.x;cyv[5]=bq.y;cyv[6]=bq.z;cyv[7]=bq.w; cyv[8]=cq.x;cyv[9]=cq.y;cyv[10]=cq.z;cyv[11]=cq.w;
        a = *(const float4*)(cz + l0 - 4); bq = *(const float4*)(cz + l0); cq = *(const float4*)(cz + l0 + 4);
        czv[0]=a.x;czv[1]=a.y;czv[2]=a.z;czv[3]=a.w; czv[4]=bq.x;czv[5]=bq.y;czv[6]=bq.z;czv[7]=bq.w; czv[8]=cq.x;czv[9]=cq.y;czv[10]=cq.z;czv[11]=cq.w;
    } else {
        #pragma unroll
        for (int j = 0; j < 12; ++j) {
            int p = l0 - 4 + j;
            p = p < 0 ? 0 : (p >= NN ? NN - 1 : p);  // clamp: OOB taps hit x==0 anyway
            cxv[j] = cx[p]; cyv[j] = cy[p]; czv[j] = cz[p];
        }
    }

    const float* xbase = x + ((size_t)b * CC + cg * CH) * NN;

    // stage loader: center quad always; halo quads only on edge lanes
    auto loadStage = [&](int i) -> Stage {
        Stage s;
        const float* xp = xbase + (size_t)i * NN;
        s.M = *(const float4*)(xp + l0);                       // always in-bounds
        if (lane == 0) {
            if (l0 >= 4) s.L = *(const float4*)(xp + l0 - 4);
            else         s.L = make_float4(0.f, 0.f, 0.f, 0.f);   // zero-pad
        }
        if (lane == 63) {
            if (l0 + 8 <= NN) s.R = *(const float4*)(xp + l0 + 4);
            else              s.R = make_float4(0.f, 0.f, 0.f, 0.f); // zero-pad
        }
        return s;
    };

    // --- issue ch0 stage before the dw chain (overlap) ---
    Stage S0 = loadStage(0);
    Stage S1;

    // --- dw[jl][k]: distance weights, shared across channels ---
    float dw[4][KK];
    #pragma unroll
    for (int jl = 0; jl < 4; ++jl) {
        const float ccx = cxv[jl + 4], ccy = cyv[jl + 4], ccz = czv[jl + 4];
        #pragma unroll
        for (int k = 0; k < KK; ++k) {
            const float dx = cxv[jl + k] - ccx;
            const float dy = cyv[jl + k] - ccy;
            const float dz = czv[jl + k] - ccz;
            const float sq = fmaf(dx, dx, fmaf(dy, dy, dz * dz));
            const float dist = __builtin_amdgcn_sqrtf(sq);   // v_sqrt_f32; sqrt(0)==0
            dw[jl][k] = fmaxf(fmaf(-inv_sigma, dist, 1.0f), 0.0f);
        }
    }

    // --- compute one channel from its stage ---
    auto compute = [&](int i, const Stage& s) {
        // halo quads from neighbor lanes (their M is our L/R window)
        float lx0 = __shfl_up(s.M.x, 1);
        float lx1 = __shfl_up(s.M.y, 1);
        float lx2 = __shfl_up(s.M.z, 1);
        float lx3 = __shfl_up(s.M.w, 1);
        float rx0 = __shfl_down(s.M.x, 1);
        float rx1 = __shfl_down(s.M.y, 1);
        float rx2 = __shfl_down(s.M.z, 1);
        float rx3 = __shfl_down(s.M.w, 1);
        if (lane == 0)  { lx0 = s.L.x; lx1 = s.L.y; lx2 = s.L.z; lx3 = s.L.w; }
        if (lane == 63) { rx0 = s.R.x; rx1 = s.R.y; rx2 = s.R.z; rx3 = s.R.w; }

        const float* wr = weight + (size_t)(cg * CH + i) * KK;  // wave-uniform
        float w[KK];
        #pragma unroll
        for (int k = 0; k < KK; ++k) w[k] = wr[k];

        const float xv[12] = {lx0, lx1, lx2, lx3,
                              s.M.x, s.M.y, s.M.z, s.M.w,
                              rx0, rx1, rx2, rx3};
        float acc[4] = {0.f, 0.f, 0.f, 0.f};
        #pragma unroll
        for (int jl = 0; jl < 4; ++jl)
            #pragma unroll
            for (int k = 0; k < KK; ++k)
                acc[jl] = fmaf(xv[jl + k] * dw[jl][k], w[k], acc[jl]);

        float4 o; o.x = acc[0]; o.y = acc[1]; o.z = acc[2]; o.w = acc[3];
        *(float4*)(out + ((size_t)b * CC + cg * CH + i) * NN + l0) = o;
    };

    // --- 1-deep pipelined channel sequence (load i+1, compute i) ---
    S1 = loadStage(1); compute(0, S0);
    S0 = loadStage(2); compute(1, S1);
    S1 = loadStage(3); compute(2, S0);
    S0 = loadStage(4); compute(3, S1);
    S1 = loadStage(5); compute(4, S0);
    S0 = loadStage(6); compute(5, S1);
    S1 = loadStage(7); compute(6, S0);
    compute(7, S1);
}

extern "C" void kernel_launch(void* const* d_in, const int* in_sizes, int n_in,
                              void* d_out, int out_size, void* d_ws, size_t ws_size,
                              hipStream_t stream) {
    const float* x      = (const float*)d_in[0];
    const float* coords = (const float*)d_in[1];
    const float* sigma  = (const float*)d_in[2];
    const float* weight = (const float*)d_in[3];
    float* out = (float*)d_out;

    dim3 grid(BB * LTILES * CGROUPS);   // 1024 blocks
    sepwconv_kernel<<<grid, THREADS, 0, stream>>>(x, coords, sigma, weight, out);
}

// Round 10
// 18.626 us; speedup vs baseline: 1.4769x; 1.0138x over previous
//
#include <hip/hip_runtime.h>

// SeparableWeightedConv R9: R8 + (1) shuffle-halo COORD loads (same trick as
// x: center quads only, halo via __shfl, real loads on lanes 0/63) cutting
// coord load-path traffic 3x; (2) nontemporal out stores (out never re-read).

#define BB 8
#define CC 128
#define NN 8192
#define KK 9

constexpr int CH      = 8;            // channels per block
constexpr int CGROUPS = CC / CH;      // 16
constexpr int LTILE   = 1024;         // 256 thr x 4 l
constexpr int LTILES  = NN / LTILE;   // 8
constexpr int THREADS = 256;

typedef float vfloat4 __attribute__((ext_vector_type(4)));

struct Stage { float4 M, L, R; };     // L/R only meaningful on lanes 0/63

__global__ __launch_bounds__(THREADS)
void sepwconv_kernel(const float* __restrict__ x,
                     const float* __restrict__ coords,
                     const float* __restrict__ sigma,
                     const float* __restrict__ weight,
                     float* __restrict__ out)
{
    const int bid = blockIdx.x;
    const int cg  = bid % CGROUPS;
    const int lt  = (bid / CGROUPS) % LTILES;
    const int b   = bid / (CGROUPS * LTILES);
    const int t   = threadIdx.x;
    const int lane = t & 63;
    const int l0  = lt * LTILE + t * 4;

    const float inv_sigma = 1.0f / sigma[0];

    const float* cx = coords + (size_t)(b * 3 + 0) * NN;
    const float* cy = coords + (size_t)(b * 3 + 1) * NN;
    const float* cz = coords + (size_t)(b * 3 + 2) * NN;

    // --- coord center quads (always in-bounds) ---
    float4 cxm = *(const float4*)(cx + l0);
    float4 cym = *(const float4*)(cy + l0);
    float4 czm = *(const float4*)(cz + l0);

    // edge-lane halo loads (lane 0: left, lane 63: right); OOB -> 0 (x==0 kills those taps)
    float4 cxL = {0,0,0,0}, cyL = {0,0,0,0}, czL = {0,0,0,0};
    float4 cxR = {0,0,0,0}, cyR = {0,0,0,0}, czR = {0,0,0,0};
    if (lane == 0 && l0 >= 4) {
        cxL = *(const float4*)(cx + l0 - 4);
        cyL = *(const float4*)(cy + l0 - 4);
        czL = *(const float4*)(cz + l0 - 4);
    }
    if (lane == 63 && l0 + 8 <= NN) {
        cxR = *(const float4*)(cx + l0 + 4);
        cyR = *(const float4*)(cy + l0 + 4);
        czR = *(const float4*)(cz + l0 + 4);
    }

    const float* xbase = x + ((size_t)b * CC + cg * CH) * NN;

    // x stage loader: center quad always; halo quads only on edge lanes
    auto loadStage = [&](int i) -> Stage {
        Stage s;
        const float* xp = xbase + (size_t)i * NN;
        s.M = *(const float4*)(xp + l0);
        s.L = make_float4(0.f, 0.f, 0.f, 0.f);
        s.R = make_float4(0.f, 0.f, 0.f, 0.f);
        if (lane == 0 && l0 >= 4)        s.L = *(const float4*)(xp + l0 - 4);
        if (lane == 63 && l0 + 8 <= NN)  s.R = *(const float4*)(xp + l0 + 4);
        return s;
    };

    // issue ch0 x stage before the dw chain (overlap)
    Stage S0 = loadStage(0);
    Stage S1;

    // --- build 12-wide coord windows via wave shuffles ---
    auto haloWindow = [&](const float4& M, const float4& L, const float4& R, float* v) {
        v[4] = M.x; v[5] = M.y; v[6] = M.z; v[7] = M.w;
        v[0] = __shfl_up(M.x, 1);
        v[1] = __shfl_up(M.y, 1);
        v[2] = __shfl_up(M.z, 1);
        v[3] = __shfl_up(M.w, 1);
        v[8]  = __shfl_down(M.x, 1);
        v[9]  = __shfl_down(M.y, 1);
        v[10] = __shfl_down(M.z, 1);
        v[11] = __shfl_down(M.w, 1);
        if (lane == 0)  { v[0] = L.x; v[1] = L.y; v[2] = L.z; v[3] = L.w; }
        if (lane == 63) { v[8] = R.x; v[9] = R.y; v[10] = R.z; v[11] = R.w; }
    };

    float cxv[12], cyv[12], czv[12];
    haloWindow(cxm, cxL, cxR, cxv);
    haloWindow(cym, cyL, cyR, cyv);
    haloWindow(czm, czL, czR, czv);

    // --- dw[jl][k]: distance weights, shared across channels ---
    float dw[4][KK];
    #pragma unroll
    for (int jl = 0; jl < 4; ++jl) {
        const float ccx = cxv[jl + 4], ccy = cyv[jl + 4], ccz = czv[jl + 4];
        #pragma unroll
        for (int k = 0; k < KK; ++k) {
            const float dx = cxv[jl + k] - ccx;
            const float dy = cyv[jl + k] - ccy;
            const float dz = czv[jl + k] - ccz;
            const float sq = fmaf(dx, dx, fmaf(dy, dy, dz * dz));
            const float dist = __builtin_amdgcn_sqrtf(sq);   // v_sqrt_f32; sqrt(0)==0
            dw[jl][k] = fmaxf(fmaf(-inv_sigma, dist, 1.0f), 0.0f);
        }
    }

    // --- compute one channel from its stage ---
    auto compute = [&](int i, const Stage& s) {
        float lx0 = __shfl_up(s.M.x, 1);
        float lx1 = __shfl_up(s.M.y, 1);
        float lx2 = __shfl_up(s.M.z, 1);
        float lx3 = __shfl_up(s.M.w, 1);
        float rx0 = __shfl_down(s.M.x, 1);
        float rx1 = __shfl_down(s.M.y, 1);
        float rx2 = __shfl_down(s.M.z, 1);
        float rx3 = __shfl_down(s.M.w, 1);
        if (lane == 0)  { lx0 = s.L.x; lx1 = s.L.y; lx2 = s.L.z; lx3 = s.L.w; }
        if (lane == 63) { rx0 = s.R.x; rx1 = s.R.y; rx2 = s.R.z; rx3 = s.R.w; }

        const float* wr = weight + (size_t)(cg * CH + i) * KK;  // wave-uniform
        float w[KK];
        #pragma unroll
        for (int k = 0; k < KK; ++k) w[k] = wr[k];

        const float xv[12] = {lx0, lx1, lx2, lx3,
                              s.M.x, s.M.y, s.M.z, s.M.w,
                              rx0, rx1, rx2, rx3};
        float acc[4] = {0.f, 0.f, 0.f, 0.f};
        #pragma unroll
        for (int jl = 0; jl < 4; ++jl)
            #pragma unroll
            for (int k = 0; k < KK; ++k)
                acc[jl] = fmaf(xv[jl + k] * dw[jl][k], w[k], acc[jl]);

        vfloat4 o = {acc[0], acc[1], acc[2], acc[3]};
        __builtin_nontemporal_store(o, (vfloat4*)(out + ((size_t)b * CC + cg * CH + i) * NN + l0));
    };

    // --- 1-deep pipelined channel sequence (load i+1, compute i) ---
    S1 = loadStage(1); compute(0, S0);
    S0 = loadStage(2); compute(1, S1);
    S1 = loadStage(3); compute(2, S0);
    S0 = loadStage(4); compute(3, S1);
    S1 = loadStage(5); compute(4, S0);
    S0 = loadStage(6); compute(5, S1);
    S1 = loadStage(7); compute(6, S0);
    compute(7, S1);
}

extern "C" void kernel_launch(void* const* d_in, const int* in_sizes, int n_in,
                              void* d_out, int out_size, void* d_ws, size_t ws_size,
                              hipStream_t stream) {
    const float* x      = (const float*)d_in[0];
    const float* coords = (const float*)d_in[1];
    const float* sigma  = (const float*)d_in[2];
    const float* weight = (const float*)d_in[3];
    float* out = (float*)d_out;

    dim3 grid(BB * LTILES * CGROUPS);   // 1024 blocks
    sepwconv_kernel<<<grid, THREADS, 0, stream>>>(x, coords, sigma, weight, out);
}